// Round 19
// baseline (86.661 us; speedup 1.0000x reference)
//
#include <hip/hip_runtime.h>

#define TT 2048
#define EMB 1024
#define NH 16
#define HD 64
#define CTX 250

typedef __attribute__((ext_vector_type(4))) float f32x4;
typedef __attribute__((ext_vector_type(8))) short s16x8;
typedef __attribute__((ext_vector_type(4))) short s16x4;

#define LDS_PTR(p) ((__attribute__((address_space(3))) void*)(p))
#define GLB_PTR(p) ((const __attribute__((address_space(1))) void*)(p))

__device__ __forceinline__ short f2bf(float f) {
  union { float f; unsigned u; } v; v.f = f;
  unsigned r = v.u + 0x7fffu + ((v.u >> 16) & 1u);
  return (short)(r >> 16);
}
__device__ __forceinline__ float bf2f(unsigned short u) {
  union { unsigned u; float f; } v; v.u = ((unsigned)u) << 16;
  return v.f;
}

// converts the three f32 inputs to bf16 AND builds the RoPE cos/sin table
__global__ void cvt_all(const float* __restrict__ q, const float* __restrict__ wi,
                        const float* __restrict__ wo, short* __restrict__ qo,
                        short* __restrict__ wio, short* __restrict__ woo,
                        float2* __restrict__ tbl) {
  int i = blockIdx.x * blockDim.x + threadIdx.x;
  if (i >= 2097152) {              // table blocks: 16384 threads x 4 entries
    int tix = (i - 2097152) * 4;
#pragma unroll
    for (int e = 0; e < 4; ++e) {
      int idx = tix + e;
      int t = idx >> 5, fi = idx & 31;
      float freq = __expf(-(float)fi * 0.2878231366f);  // ln(10000)/32
      float s, c;
      sincosf((float)t * freq, &s, &c);
      tbl[idx] = make_float2(c, s);
    }
    return;
  }
  const float* src; short* dst; int off;
  if (i < 1048576)      { src = q;  dst = qo;  off = i; }
  else if (i < 1835008) { src = wi; dst = wio; off = i - 1048576; }
  else                  { src = wo; dst = woo; off = i - 1835008; }
  float4 v = reinterpret_cast<const float4*>(src)[off];
  s16x4 o; o[0] = f2bf(v.x); o[1] = f2bf(v.y); o[2] = f2bf(v.z); o[3] = f2bf(v.w);
  *reinterpret_cast<s16x4*>(dst + off * 4) = o;
}

// ---------------------------------------------------------------------------
// QKV GEMM — R18 structure (8 waves, BK=64, 16B-slot swizzle, fused lane-local
// RoPE epilogue) + __launch_bounds__(512, 8): forces VGPR <= 64 so waves land
// in the 8-waves/SIMD allocation class -> all 3 blocks/CU co-resident
// (24 waves/CU). At VGPR=68 (R16-R18) only 2 blocks fit; the third serialized.
// ---------------------------------------------------------------------------
__global__ __launch_bounds__(512, 8) void gemm_qkv(const short* __restrict__ A,
                                                   const short* __restrict__ W,
                                                   short* __restrict__ Qb,
                                                   short* __restrict__ Kb,
                                                   short* __restrict__ Vt,
                                                   const float2* __restrict__ tbl,
                                                   int N, int K) {
  constexpr int BM = 128, BK = 64, MFR = 2;
  __shared__ __align__(16) short As[BM * BK];   // 16KB: 8 segs x 2 halves x 1KB
  __shared__ __align__(16) short Bs[128 * BK];  // 16KB
  const int lane = threadIdx.x & 63;
  const int wid  = threadIdx.x >> 6;          // 0..7
  const int lr = lane & 15, lg = lane >> 4;
  // 2D XCD-chunked mapping: 768 blocks = 8 XCDs x (12 x 8)
  const int xcd = blockIdx.x & 7;
  const int sub = blockIdx.x >> 3;
  const int bx = (sub % 12) + 12 * (xcd & 1);
  const int by = (sub / 12) + 8 * (xcd >> 1);
  const int rblk = by * BM;
  const int cblk = bx * 128;
  const int wrow = (wid >> 1) * 32;           // 4 M-waves
  const int wcol = (wid & 1) * 64;            // 2 N-waves
  const int sel = cblk >> 10;                 // 0=Q 1=K 2=V (block-uniform)
  // 16B-slot swizzled staging (verified R13/R16/R17)
  const int lrow = lane >> 2;
  const int fst  = (lrow & 3) ^ ((lrow >> 2) & 3);
  const int schunk = ((lane & 3) ^ fst) * 8;
  const int frd = (lr & 3) ^ ((lr >> 2) & 3);
  const int rd_off = lr * 32 + ((lg ^ frd) * 8);
  // per-wave staging base rows (A linear; W permuted for Q/K RoPE pairing)
  const int p = wid * 16 + lrow;
  const int prow = (sel < 2) ? ((p & 64) + 2 * (p & 31) + ((p >> 5) & 1)) : p;
  const short* Abase = A + (size_t)(rblk + p) * K + schunk;
  const short* Wbase = W + (size_t)(cblk + prow) * K + schunk;
  f32x4 acc[MFR][4] = {};

  for (int kk = 0; kk < K; kk += BK) {
#pragma unroll
    for (int h = 0; h < 2; h++) {
      __builtin_amdgcn_global_load_lds(GLB_PTR(Abase + kk + h * 32),
                                       LDS_PTR(&As[(wid * 2 + h) * 512]), 16, 0, 0);
      __builtin_amdgcn_global_load_lds(GLB_PTR(Wbase + kk + h * 32),
                                       LDS_PTR(&Bs[(wid * 2 + h) * 512]), 16, 0, 0);
    }
    __syncthreads();
#pragma unroll
    for (int kh = 0; kh < 2; kh++) {
      s16x8 af[MFR], bfr[4];
#pragma unroll
      for (int m = 0; m < MFR; m++)
        af[m] = *reinterpret_cast<const s16x8*>(
            &As[(((wid >> 1) * 2 + m) * 2 + kh) * 512 + rd_off]);
#pragma unroll
      for (int n = 0; n < 4; n++)
        bfr[n] = *reinterpret_cast<const s16x8*>(
            &Bs[(((wid & 1) * 4 + n) * 2 + kh) * 512 + rd_off]);
#pragma unroll
      for (int m = 0; m < MFR; m++)
#pragma unroll
        for (int n = 0; n < 4; n++)
          acc[m][n] = __builtin_amdgcn_mfma_f32_16x16x32_bf16(af[m], bfr[n], acc[m][n], 0, 0, 0);
    }
    __syncthreads();
  }

  // ---------------- fused lane-local RoPE epilogue (unchanged) ----------------
  if (sel == 2) {
    const int dcol_base = (cblk & 1023) + wcol;
#pragma unroll
    for (int m = 0; m < MFR; m++) {
      int trow = rblk + wrow + m * 16 + lg * 4;
      int b = trow >> 11;
      int tq = trow & 2047;
#pragma unroll
      for (int n = 0; n < 4; n++) {
        int dcol = dcol_base + n * 16 + lr;
        int h = dcol >> 6;
        int d = dcol & 63;
        size_t bh = (size_t)(b * NH + h);
        s16x4 pk;
#pragma unroll
        for (int r = 0; r < 4; r++) pk[r] = f2bf(acc[m][n][r]);
        *reinterpret_cast<s16x4*>(Vt + (bh * HD + d) * TT + tq) = pk;
      }
    }
  } else {
    short* dst = (sel == 0) ? Qb : Kb;
    const int h = ((cblk & 1023) + wcol) >> 6;      // wave-uniform head
#pragma unroll
    for (int m = 0; m < MFR; m++) {
      int trow = rblk + wrow + m * 16 + lg * 4;
      int b = trow >> 11;
      int tq = trow & 2047;
      size_t bh = (size_t)(b * NH + h);
#pragma unroll
      for (int n = 0; n < 2; n++) {
        int i = n * 16 + lr;                        // rotation index in [0,32)
        const float2* tp = tbl + (size_t)tq * 32 + i;
#pragma unroll
        for (int r = 0; r < 4; r++) {
          float xa = acc[m][n][r];
          float xb = acc[m][n + 2][r];
          float2 cs = tp[r * 32];
          float ya = xa * cs.x - xb * cs.y;
          float yb = xa * cs.y + xb * cs.x;
          unsigned pk = ((unsigned)(unsigned short)f2bf(yb) << 16) |
                        (unsigned short)f2bf(ya);
          *reinterpret_cast<unsigned*>(dst + (bh * TT + tq + r) * HD + 2 * i) = pk;
        }
      }
    }
  }
}

// ---------------------------------------------------------------------------
// Out-projection GEMM — 8-wave + forced <=64-VGPR class (same lever).
// BM=64, BN=128, BK=32, 512 thr; wave grid 4M x 2N, acc[1][4]. f32 out.
// ---------------------------------------------------------------------------
__global__ __launch_bounds__(512, 8) void gemm_out8(const short* __restrict__ A,
                                                    const short* __restrict__ W,
                                                    float* __restrict__ C, int N, int K) {
  constexpr int BM = 64, BK = 32;
  __shared__ __align__(16) short As[BM * BK];   // 4KB: 4 segs
  __shared__ __align__(16) short Bs[128 * BK];  // 8KB: 8 segs
  const int lane = threadIdx.x & 63;
  const int wid  = threadIdx.x >> 6;          // 0..7
  const int lr = lane & 15, lg = lane >> 4;
  // XCD-chunked: 512 blocks = 8 XCDs x (4 x 16)
  const int xcd = blockIdx.x & 7;
  const int sub = blockIdx.x >> 3;
  const int bx = (sub % 4) + 4 * (xcd & 1);
  const int by = (sub / 4) + 16 * (xcd >> 1);
  const int rblk = by * BM;
  const int cblk = bx * 128;
  const int wm = wid >> 1;                    // 4 M-waves (16 rows each)
  const int wn = wid & 1;                     // 2 N-waves (64 cols each)
  // 16B-slot swizzled staging
  const int lrow = lane >> 2;
  const int fst  = (lrow & 3) ^ ((lrow >> 2) & 3);
  const int schunk = ((lane & 3) ^ fst) * 8;
  const int frd = (lr & 3) ^ ((lr >> 2) & 3);
  const int rd_off = lr * 32 + ((lg ^ frd) * 8);
  const short* Abase = A + (size_t)(rblk + wid * 16 + lrow) * K + schunk;  // wid<4 only
  const short* Wbase = W + (size_t)(cblk + wid * 16 + lrow) * K + schunk;
  f32x4 acc[4] = {};

  for (int kk = 0; kk < K; kk += BK) {
    if (wid < 4)
      __builtin_amdgcn_global_load_lds(GLB_PTR(Abase + kk), LDS_PTR(&As[wid * 512]), 16, 0, 0);
    __builtin_amdgcn_global_load_lds(GLB_PTR(Wbase + kk), LDS_PTR(&Bs[wid * 512]), 16, 0, 0);
    __syncthreads();
    s16x8 af, bfr[4];
    af = *reinterpret_cast<const s16x8*>(&As[wm * 512 + rd_off]);
#pragma unroll
    for (int n = 0; n < 4; n++)
      bfr[n] = *reinterpret_cast<const s16x8*>(&Bs[(wn * 4 + n) * 512 + rd_off]);
#pragma unroll
    for (int n = 0; n < 4; n++)
      acc[n] = __builtin_amdgcn_mfma_f32_16x16x32_bf16(af, bfr[n], acc[n], 0, 0, 0);
    __syncthreads();
  }
#pragma unroll
  for (int n = 0; n < 4; n++)
#pragma unroll
    for (int r = 0; r < 4; r++) {
      int row = rblk + wm * 16 + lg * 4 + r;
      int col = cblk + wn * 64 + n * 16 + lr;
      C[(size_t)row * N + col] = acc[n][r];
    }
}

// attn v4: shuffle-free softmax (no max shift; denominator via ones-column
// MFMA). 4-wave blocks, K/V staged once per block, XCD-chunked.
__global__ __launch_bounds__(256) void attn_v4(const short* __restrict__ Qb,
                                               const short* __restrict__ Kb,
                                               const short* __restrict__ Vt,
                                               short* __restrict__ Xout) {
  int tid = threadIdx.x;
  int lane = tid & 63;
  int w = tid >> 6;
  int lr = lane & 15, lg = lane >> 4;
  int id = blockIdx.x;
  int xcd = id & 7;
  int sub = id >> 3;
  int bh = xcd * 4 + (sub >> 5);
  int tblk = (sub & 31) * 64;
  int t0 = tblk + w * 16;
  int b = bh >> 4, h = bh & 15;
  const short* Qp = Qb + bh * TT * HD;
  const char* Kp = (const char*)(Kb + bh * TT * HD);
  const char* Vtp = (const char*)(Vt + bh * HD * TT);
  __shared__ __align__(16) short Ks[32 * 64];
  __shared__ __align__(16) short Vs[64 * 32];
  __shared__ __align__(16) short p_lds[4][16][40];
  s16x8 qf[2];
#pragma unroll
  for (int d2 = 0; d2 < 2; d2++)
    qf[d2] = *reinterpret_cast<const s16x8*>(Qp + (t0 + lr) * HD + d2 * 32 + lg * 8);
  s16x8 ones;
#pragma unroll
  for (int j = 0; j < 8; j++) ones[j] = (short)0x3F80;  // bf16 1.0
  f32x4 of[4] = {};
  f32x4 ofl = {};
  int lo = tblk - (CTX - 1); if (lo < 0) lo = 0;
  int kt_lo = lo & ~31;
  int kt_hi = (tblk + 63) & ~31;
  int krow = w * 8 + (lane >> 3);
  int kcb  = ((lane & 7) * 16) ^ ((krow & 7) << 4);
  int vd   = w * 16 + (lane >> 2);
  int vcb  = ((lane & 3) * 16) ^ (((vd >> 1) & 3) << 4);
  char* ksdst = (char*)Ks + w * 1024 + lane * 16;
  char* vsdst = (char*)Vs + w * 1024 + lane * 16;
  for (int kt = kt_lo; kt <= kt_hi; kt += 32) {
    __builtin_amdgcn_global_load_lds(GLB_PTR(Kp + (kt + krow) * 128 + kcb),
                                     LDS_PTR(ksdst), 16, 0, 0);
    __builtin_amdgcn_global_load_lds(GLB_PTR(Vtp + vd * (TT * 2) + kt * 2 + vcb),
                                     LDS_PTR(vsdst), 16, 0, 0);
    __syncthreads();
    if (kt <= t0 + 15 && kt + 31 >= t0 - (CTX - 1)) {
      f32x4 s2[2];
#pragma unroll
      for (int hh = 0; hh < 2; hh++) {
        int row = hh * 16 + lr;
        f32x4 sa = {};
#pragma unroll
        for (int d2 = 0; d2 < 2; d2++) {
          int cb = (d2 * 64 + lg * 16) ^ ((row & 7) << 4);
          s16x8 kf = *reinterpret_cast<const s16x8*>((const char*)Ks + row * 128 + cb);
          sa = __builtin_amdgcn_mfma_f32_16x16x32_bf16(qf[d2], kf, sa, 0, 0, 0);
        }
        s2[hh] = sa;
      }
#pragma unroll
      for (int r = 0; r < 4; r++) {
        int row = t0 + lg * 4 + r;
#pragma unroll
        for (int hh = 0; hh < 2; hh++) {
          int col = kt + hh * 16 + lr;
          int dl = row - col;
          bool vdm = (dl >= 0) && (dl < CTX);
          float pv = vdm ? __expf(s2[hh][r] * 0.125f) : 0.0f;
          p_lds[w][lg * 4 + r][hh * 16 + lr] = f2bf(pv);
        }
      }
      s16x8 pa = *reinterpret_cast<const s16x8*>(&p_lds[w][lr][lg * 8]);
#pragma unroll
      for (int n = 0; n < 4; n++) {
        int d = n * 16 + lr;
        int cb = (lg * 16) ^ (((d >> 1) & 3) << 4);
        s16x8 vf = *reinterpret_cast<const s16x8*>((const char*)Vs + d * 64 + cb);
        of[n] = __builtin_amdgcn_mfma_f32_16x16x32_bf16(pa, vf, of[n], 0, 0, 0);
      }
      ofl = __builtin_amdgcn_mfma_f32_16x16x32_bf16(pa, ones, ofl, 0, 0, 0);
    }
    __syncthreads();
  }
#pragma unroll
  for (int r = 0; r < 4; r++) {
    float inv = 1.0f / ofl[r];
    int row = t0 + lg * 4 + r;
#pragma unroll
    for (int n = 0; n < 4; n++)
      Xout[(b * TT + row) * EMB + h * HD + n * 16 + lr] = f2bf(of[n][r] * inv);
  }
}

extern "C" void kernel_launch(void* const* d_in, const int* in_sizes, int n_in,
                              void* d_out, int out_size, void* d_ws, size_t ws_size,
                              hipStream_t stream) {
  const float* query = (const float*)d_in[0];
  const float* w_in  = (const float*)d_in[1];
  const float* w_out = (const float*)d_in[2];
  char* ws = (char*)d_ws;
  short* qbf   = (short*)(ws + 0);          //  8388608  query bf16 [4096][1024]
  short* wibf  = (short*)(ws + 8388608);    //  6291456  in_proj bf16 [3072][1024]
  short* wobf  = (short*)(ws + 14680064);   //  2097152  out_proj bf16 [1024][1024]
  float2* tbl  = (float2*)(ws + 16777216);  //   524288  RoPE cos/sin [2048][32]
  short* attnx = (short*)(ws + 17301504);   //  8388608  attn out bf16 [4096][1024]
  short* Qb    = (short*)(ws + 41943040);   //  8388608  [B][H][T][D]
  short* Kb    = (short*)(ws + 50331648);   //  8388608  [B][H][T][D]
  short* Vt    = (short*)(ws + 58720256);   //  8388608  [B][H][D][T]

  cvt_all<<<8256, 256, 0, stream>>>(query, w_in, w_out, qbf, wibf, wobf, tbl);
  gemm_qkv<<<768, 512, 0, stream>>>(qbf, wibf, Qb, Kb, Vt, tbl, 3072, 1024);
  attn_v4<<<1024, 256, 0, stream>>>(Qb, Kb, Vt, attnx);
  gemm_out8<<<512, 512, 0, stream>>>(attnx, wobf, (float*)d_out, 1024, 1024);
}

// Round 20
// 85.012 us; speedup vs baseline: 1.0194x; 1.0194x over previous
//
#include <hip/hip_runtime.h>

#define TT 2048
#define EMB 1024
#define NH 16
#define HD 64
#define CTX 250

typedef __attribute__((ext_vector_type(4))) float f32x4;
typedef __attribute__((ext_vector_type(8))) short s16x8;
typedef __attribute__((ext_vector_type(4))) short s16x4;

#define LDS_PTR(p) ((__attribute__((address_space(3))) void*)(p))
#define GLB_PTR(p) ((const __attribute__((address_space(1))) void*)(p))

__device__ __forceinline__ short f2bf(float f) {
  union { float f; unsigned u; } v; v.f = f;
  unsigned r = v.u + 0x7fffu + ((v.u >> 16) & 1u);
  return (short)(r >> 16);
}
__device__ __forceinline__ float bf2f(unsigned short u) {
  union { unsigned u; float f; } v; v.u = ((unsigned)u) << 16;
  return v.f;
}

// converts the three f32 inputs to bf16 AND builds the RoPE cos/sin table
__global__ void cvt_all(const float* __restrict__ q, const float* __restrict__ wi,
                        const float* __restrict__ wo, short* __restrict__ qo,
                        short* __restrict__ wio, short* __restrict__ woo,
                        float2* __restrict__ tbl) {
  int i = blockIdx.x * blockDim.x + threadIdx.x;
  if (i >= 2097152) {              // table blocks: 16384 threads x 4 entries
    int tix = (i - 2097152) * 4;
#pragma unroll
    for (int e = 0; e < 4; ++e) {
      int idx = tix + e;
      int t = idx >> 5, fi = idx & 31;
      float freq = __expf(-(float)fi * 0.2878231366f);  // ln(10000)/32
      float s, c;
      sincosf((float)t * freq, &s, &c);
      tbl[idx] = make_float2(c, s);
    }
    return;
  }
  const float* src; short* dst; int off;
  if (i < 1048576)      { src = q;  dst = qo;  off = i; }
  else if (i < 1835008) { src = wi; dst = wio; off = i - 1048576; }
  else                  { src = wo; dst = woo; off = i - 1835008; }
  float4 v = reinterpret_cast<const float4*>(src)[off];
  s16x4 o; o[0] = f2bf(v.x); o[1] = f2bf(v.y); o[2] = f2bf(v.z); o[3] = f2bf(v.w);
  *reinterpret_cast<s16x4*>(dst + off * 4) = o;
}

// ---------------------------------------------------------------------------
// QKV GEMM — R18 best config (8 waves, BK=64, 16B-slot swizzle, fused
// lane-local RoPE epilogue). launch_bounds reverted to plain 512 (R19's
// forced 8-waves/EU class regressed).
// ---------------------------------------------------------------------------
__global__ __launch_bounds__(512) void gemm_qkv(const short* __restrict__ A,
                                                const short* __restrict__ W,
                                                short* __restrict__ Qb,
                                                short* __restrict__ Kb,
                                                short* __restrict__ Vt,
                                                const float2* __restrict__ tbl,
                                                int N, int K) {
  constexpr int BM = 128, BK = 64, MFR = 2;
  __shared__ __align__(16) short As[BM * BK];   // 16KB
  __shared__ __align__(16) short Bs[128 * BK];  // 16KB
  const int lane = threadIdx.x & 63;
  const int wid  = threadIdx.x >> 6;          // 0..7
  const int lr = lane & 15, lg = lane >> 4;
  const int xcd = blockIdx.x & 7;
  const int sub = blockIdx.x >> 3;
  const int bx = (sub % 12) + 12 * (xcd & 1);
  const int by = (sub / 12) + 8 * (xcd >> 1);
  const int rblk = by * BM;
  const int cblk = bx * 128;
  const int wrow = (wid >> 1) * 32;           // 4 M-waves
  const int wcol = (wid & 1) * 64;            // 2 N-waves
  const int sel = cblk >> 10;                 // 0=Q 1=K 2=V (block-uniform)
  const int lrow = lane >> 2;
  const int fst  = (lrow & 3) ^ ((lrow >> 2) & 3);
  const int schunk = ((lane & 3) ^ fst) * 8;
  const int frd = (lr & 3) ^ ((lr >> 2) & 3);
  const int rd_off = lr * 32 + ((lg ^ frd) * 8);
  const int p = wid * 16 + lrow;
  const int prow = (sel < 2) ? ((p & 64) + 2 * (p & 31) + ((p >> 5) & 1)) : p;
  const short* Abase = A + (size_t)(rblk + p) * K + schunk;
  const short* Wbase = W + (size_t)(cblk + prow) * K + schunk;
  f32x4 acc[MFR][4] = {};

  for (int kk = 0; kk < K; kk += BK) {
#pragma unroll
    for (int h = 0; h < 2; h++) {
      __builtin_amdgcn_global_load_lds(GLB_PTR(Abase + kk + h * 32),
                                       LDS_PTR(&As[(wid * 2 + h) * 512]), 16, 0, 0);
      __builtin_amdgcn_global_load_lds(GLB_PTR(Wbase + kk + h * 32),
                                       LDS_PTR(&Bs[(wid * 2 + h) * 512]), 16, 0, 0);
    }
    __syncthreads();
#pragma unroll
    for (int kh = 0; kh < 2; kh++) {
      s16x8 af[MFR], bfr[4];
#pragma unroll
      for (int m = 0; m < MFR; m++)
        af[m] = *reinterpret_cast<const s16x8*>(
            &As[(((wid >> 1) * 2 + m) * 2 + kh) * 512 + rd_off]);
#pragma unroll
      for (int n = 0; n < 4; n++)
        bfr[n] = *reinterpret_cast<const s16x8*>(
            &Bs[(((wid & 1) * 4 + n) * 2 + kh) * 512 + rd_off]);
#pragma unroll
      for (int m = 0; m < MFR; m++)
#pragma unroll
        for (int n = 0; n < 4; n++)
          acc[m][n] = __builtin_amdgcn_mfma_f32_16x16x32_bf16(af[m], bfr[n], acc[m][n], 0, 0, 0);
    }
    __syncthreads();
  }

  // ---------------- fused lane-local RoPE epilogue ----------------
  if (sel == 2) {
    const int dcol_base = (cblk & 1023) + wcol;
#pragma unroll
    for (int m = 0; m < MFR; m++) {
      int trow = rblk + wrow + m * 16 + lg * 4;
      int b = trow >> 11;
      int tq = trow & 2047;
#pragma unroll
      for (int n = 0; n < 4; n++) {
        int dcol = dcol_base + n * 16 + lr;
        int h = dcol >> 6;
        int d = dcol & 63;
        size_t bh = (size_t)(b * NH + h);
        s16x4 pk;
#pragma unroll
        for (int r = 0; r < 4; r++) pk[r] = f2bf(acc[m][n][r]);
        *reinterpret_cast<s16x4*>(Vt + (bh * HD + d) * TT + tq) = pk;
      }
    }
  } else {
    short* dst = (sel == 0) ? Qb : Kb;
    const int h = ((cblk & 1023) + wcol) >> 6;      // wave-uniform head
#pragma unroll
    for (int m = 0; m < MFR; m++) {
      int trow = rblk + wrow + m * 16 + lg * 4;
      int b = trow >> 11;
      int tq = trow & 2047;
      size_t bh = (size_t)(b * NH + h);
#pragma unroll
      for (int n = 0; n < 2; n++) {
        int i = n * 16 + lr;                        // rotation index in [0,32)
        const float2* tp = tbl + (size_t)tq * 32 + i;
#pragma unroll
        for (int r = 0; r < 4; r++) {
          float xa = acc[m][n][r];
          float xb = acc[m][n + 2][r];
          float2 cs = tp[r * 32];
          float ya = xa * cs.x - xb * cs.y;
          float yb = xa * cs.y + xb * cs.x;
          unsigned pk = ((unsigned)(unsigned short)f2bf(yb) << 16) |
                        (unsigned short)f2bf(ya);
          *reinterpret_cast<unsigned*>(dst + (bh * TT + tq + r) * HD + 2 * i) = pk;
        }
      }
    }
  }
}

// ---------------------------------------------------------------------------
// Out-projection GEMM — R18 best config (8 waves, plain launch_bounds).
// ---------------------------------------------------------------------------
__global__ __launch_bounds__(512) void gemm_out8(const short* __restrict__ A,
                                                 const short* __restrict__ W,
                                                 float* __restrict__ C, int N, int K) {
  constexpr int BM = 64, BK = 32;
  __shared__ __align__(16) short As[BM * BK];   // 4KB
  __shared__ __align__(16) short Bs[128 * BK];  // 8KB
  const int lane = threadIdx.x & 63;
  const int wid  = threadIdx.x >> 6;
  const int lr = lane & 15, lg = lane >> 4;
  const int xcd = blockIdx.x & 7;
  const int sub = blockIdx.x >> 3;
  const int bx = (sub % 4) + 4 * (xcd & 1);
  const int by = (sub / 4) + 16 * (xcd >> 1);
  const int rblk = by * BM;
  const int cblk = bx * 128;
  const int wm = wid >> 1;
  const int wn = wid & 1;
  const int lrow = lane >> 2;
  const int fst  = (lrow & 3) ^ ((lrow >> 2) & 3);
  const int schunk = ((lane & 3) ^ fst) * 8;
  const int frd = (lr & 3) ^ ((lr >> 2) & 3);
  const int rd_off = lr * 32 + ((lg ^ frd) * 8);
  const short* Abase = A + (size_t)(rblk + wid * 16 + lrow) * K + schunk;  // wid<4 only
  const short* Wbase = W + (size_t)(cblk + wid * 16 + lrow) * K + schunk;
  f32x4 acc[4] = {};

  for (int kk = 0; kk < K; kk += BK) {
    if (wid < 4)
      __builtin_amdgcn_global_load_lds(GLB_PTR(Abase + kk), LDS_PTR(&As[wid * 512]), 16, 0, 0);
    __builtin_amdgcn_global_load_lds(GLB_PTR(Wbase + kk), LDS_PTR(&Bs[wid * 512]), 16, 0, 0);
    __syncthreads();
    s16x8 af, bfr[4];
    af = *reinterpret_cast<const s16x8*>(&As[wm * 512 + rd_off]);
#pragma unroll
    for (int n = 0; n < 4; n++)
      bfr[n] = *reinterpret_cast<const s16x8*>(&Bs[(wn * 4 + n) * 512 + rd_off]);
#pragma unroll
    for (int n = 0; n < 4; n++)
      acc[n] = __builtin_amdgcn_mfma_f32_16x16x32_bf16(af, bfr[n], acc[n], 0, 0, 0);
    __syncthreads();
  }
#pragma unroll
  for (int n = 0; n < 4; n++)
#pragma unroll
    for (int r = 0; r < 4; r++) {
      int row = rblk + wm * 16 + lg * 4 + r;
      int col = cblk + wn * 64 + n * 16 + lr;
      C[(size_t)row * N + col] = acc[n][r];
    }
}

// ---------------------------------------------------------------------------
// attn v5: 8-wave blocks covering 128 q-rows (512 blocks = 8 XCDs x 4 bh x
// 16 t-blocks). K/V tiles staged once per block and shared by 8 waves
// (per-q-row staging volume -38% vs v4's 64-row blocks). Waves 0-3 stage K,
// waves 4-7 stage V. Shuffle-free softmax (no max shift; denominator via
// ones-column MFMA) unchanged.
// ---------------------------------------------------------------------------
__global__ __launch_bounds__(512) void attn_v5(const short* __restrict__ Qb,
                                               const short* __restrict__ Kb,
                                               const short* __restrict__ Vt,
                                               short* __restrict__ Xout) {
  int tid = threadIdx.x;
  int lane = tid & 63;
  int w = tid >> 6;                 // 0..7
  int lr = lane & 15, lg = lane >> 4;
  int id = blockIdx.x;
  int xcd = id & 7;
  int sub = id >> 3;                // 0..63
  int bh = xcd * 4 + (sub >> 4);    // 4 bh per XCD
  int tblk = (sub & 15) * 128;
  int t0 = tblk + w * 16;
  int b = bh >> 4, h = bh & 15;
  const short* Qp = Qb + bh * TT * HD;
  const char* Kp = (const char*)(Kb + bh * TT * HD);
  const char* Vtp = (const char*)(Vt + bh * HD * TT);
  __shared__ __align__(16) short Ks[32 * 64];
  __shared__ __align__(16) short Vs[64 * 32];
  __shared__ __align__(16) short p_lds[8][16][40];
  s16x8 qf[2];
#pragma unroll
  for (int d2 = 0; d2 < 2; d2++)
    qf[d2] = *reinterpret_cast<const s16x8*>(Qp + (t0 + lr) * HD + d2 * 32 + lg * 8);
  s16x8 ones;
#pragma unroll
  for (int j = 0; j < 8; j++) ones[j] = (short)0x3F80;  // bf16 1.0
  f32x4 of[4] = {};
  f32x4 ofl = {};
  int lo = tblk - (CTX - 1); if (lo < 0) lo = 0;
  int kt_lo = lo & ~31;
  int kt_hi = (tblk + 127) & ~31;
  // staging: waves 0-3 stage K tile (4KB), waves 4-7 stage V tile (4KB)
  int krow = w * 8 + (lane >> 3);                       // valid for w<4
  int kcb  = ((lane & 7) * 16) ^ ((krow & 7) << 4);
  int vw = w - 4;
  int vd   = vw * 16 + (lane >> 2);                     // valid for w>=4
  int vcb  = ((lane & 3) * 16) ^ (((vd >> 1) & 3) << 4);
  char* ksdst = (char*)Ks + w * 1024 + lane * 16;       // w<4
  char* vsdst = (char*)Vs + vw * 1024 + lane * 16;      // w>=4
  for (int kt = kt_lo; kt <= kt_hi; kt += 32) {
    if (w < 4)
      __builtin_amdgcn_global_load_lds(GLB_PTR(Kp + (kt + krow) * 128 + kcb),
                                       LDS_PTR(ksdst), 16, 0, 0);
    else
      __builtin_amdgcn_global_load_lds(GLB_PTR(Vtp + vd * (TT * 2) + kt * 2 + vcb),
                                       LDS_PTR(vsdst), 16, 0, 0);
    __syncthreads();
    if (kt <= t0 + 15 && kt + 31 >= t0 - (CTX - 1)) {
      f32x4 s2[2];
#pragma unroll
      for (int hh = 0; hh < 2; hh++) {
        int row = hh * 16 + lr;
        f32x4 sa = {};
#pragma unroll
        for (int d2 = 0; d2 < 2; d2++) {
          int cb = (d2 * 64 + lg * 16) ^ ((row & 7) << 4);
          s16x8 kf = *reinterpret_cast<const s16x8*>((const char*)Ks + row * 128 + cb);
          sa = __builtin_amdgcn_mfma_f32_16x16x32_bf16(qf[d2], kf, sa, 0, 0, 0);
        }
        s2[hh] = sa;
      }
#pragma unroll
      for (int r = 0; r < 4; r++) {
        int row = t0 + lg * 4 + r;
#pragma unroll
        for (int hh = 0; hh < 2; hh++) {
          int col = kt + hh * 16 + lr;
          int dl = row - col;
          bool vdm = (dl >= 0) && (dl < CTX);
          float pv = vdm ? __expf(s2[hh][r] * 0.125f) : 0.0f;
          p_lds[w][lg * 4 + r][hh * 16 + lr] = f2bf(pv);
        }
      }
      s16x8 pa = *reinterpret_cast<const s16x8*>(&p_lds[w][lr][lg * 8]);
#pragma unroll
      for (int n = 0; n < 4; n++) {
        int d = n * 16 + lr;
        int cb = (lg * 16) ^ (((d >> 1) & 3) << 4);
        s16x8 vf = *reinterpret_cast<const s16x8*>((const char*)Vs + d * 64 + cb);
        of[n] = __builtin_amdgcn_mfma_f32_16x16x32_bf16(pa, vf, of[n], 0, 0, 0);
      }
      ofl = __builtin_amdgcn_mfma_f32_16x16x32_bf16(pa, ones, ofl, 0, 0, 0);
    }
    __syncthreads();
  }
#pragma unroll
  for (int r = 0; r < 4; r++) {
    float inv = 1.0f / ofl[r];
    int row = t0 + lg * 4 + r;
#pragma unroll
    for (int n = 0; n < 4; n++)
      Xout[(b * TT + row) * EMB + h * HD + n * 16 + lr] = f2bf(of[n][r] * inv);
  }
}

extern "C" void kernel_launch(void* const* d_in, const int* in_sizes, int n_in,
                              void* d_out, int out_size, void* d_ws, size_t ws_size,
                              hipStream_t stream) {
  const float* query = (const float*)d_in[0];
  const float* w_in  = (const float*)d_in[1];
  const float* w_out = (const float*)d_in[2];
  char* ws = (char*)d_ws;
  short* qbf   = (short*)(ws + 0);          //  8388608  query bf16 [4096][1024]
  short* wibf  = (short*)(ws + 8388608);    //  6291456  in_proj bf16 [3072][1024]
  short* wobf  = (short*)(ws + 14680064);   //  2097152  out_proj bf16 [1024][1024]
  float2* tbl  = (float2*)(ws + 16777216);  //   524288  RoPE cos/sin [2048][32]
  short* attnx = (short*)(ws + 17301504);   //  8388608  attn out bf16 [4096][1024]
  short* Qb    = (short*)(ws + 41943040);   //  8388608  [B][H][T][D]
  short* Kb    = (short*)(ws + 50331648);   //  8388608  [B][H][T][D]
  short* Vt    = (short*)(ws + 58720256);   //  8388608  [B][H][D][T]

  cvt_all<<<8256, 256, 0, stream>>>(query, w_in, w_out, qbf, wibf, wobf, tbl);
  gemm_qkv<<<768, 512, 0, stream>>>(qbf, wibf, Qb, Kb, Vt, tbl, 3072, 1024);
  attn_v5<<<512, 512, 0, stream>>>(Qb, Kb, Vt, attnx);
  gemm_out8<<<512, 512, 0, stream>>>(attnx, wobf, (float*)d_out, 1024, 1024);
}